// Round 1
// baseline (983.610 us; speedup 1.0000x reference)
//
#include <hip/hip_runtime.h>

#define LN_EPS 1e-5f

// ---------------- transpose weight (N=128 rows, K cols) -> Wt (K x 128) ----
__global__ __launch_bounds__(256) void transpose_w(const float* __restrict__ in,
                                                   float* __restrict__ out, int K) {
  int n = blockIdx.y;                       // 0..127
  int k = blockIdx.x * 256 + threadIdx.x;   // 0..K-1
  if (k < K) out[(size_t)k * 128 + n] = in[(size_t)n * K + k];
}

// ---------------- out(M x 128) = X(M x K) @ Wt(K x 128) + bias ----------------
template <int K>
__global__ __launch_bounds__(256) void gemm_bias(const float* __restrict__ X,
                                                 const float* __restrict__ Wt,
                                                 const float* __restrict__ bias,
                                                 float* __restrict__ out, int M) {
  constexpr int KK = 32;
  __shared__ float Xs[64][KK + 1];
  __shared__ float Ws[KK][128];
  const int tid = threadIdx.x;
  const int tx = tid & 15, ty = tid >> 4;   // tx: col group (8 cols), ty: row group (4 rows)
  const int row0 = blockIdx.x * 64;

  float acc[4][8];
#pragma unroll
  for (int i = 0; i < 4; ++i)
#pragma unroll
    for (int c = 0; c < 8; ++c) acc[i][c] = 0.f;

  for (int k0 = 0; k0 < K; k0 += KK) {
    // stage X tile: 64 x 32 floats
#pragma unroll
    for (int it = 0; it < 2; ++it) {
      int q = tid + it * 256;               // [0,512) float4 id
      int r = q >> 3, kq = (q & 7) * 4;
      float4 v = make_float4(0.f, 0.f, 0.f, 0.f);
      int grow = row0 + r;
      if (grow < M) v = *reinterpret_cast<const float4*>(&X[(size_t)grow * K + k0 + kq]);
      Xs[r][kq + 0] = v.x; Xs[r][kq + 1] = v.y; Xs[r][kq + 2] = v.z; Xs[r][kq + 3] = v.w;
    }
    // stage W tile: 32 x 128 floats
#pragma unroll
    for (int it = 0; it < 4; ++it) {
      int q = tid + it * 256;               // [0,1024) float4 id
      int kr = q >> 5, col = (q & 31) * 4;
      *reinterpret_cast<float4*>(&Ws[kr][col]) =
          *reinterpret_cast<const float4*>(&Wt[(size_t)(k0 + kr) * 128 + col]);
    }
    __syncthreads();
#pragma unroll
    for (int k = 0; k < KK; ++k) {
      float xv[4];
#pragma unroll
      for (int i = 0; i < 4; ++i) xv[i] = Xs[ty * 4 + i][k];
      float4 wa = *reinterpret_cast<const float4*>(&Ws[k][tx * 8]);
      float4 wb = *reinterpret_cast<const float4*>(&Ws[k][tx * 8 + 4]);
      float wv[8] = {wa.x, wa.y, wa.z, wa.w, wb.x, wb.y, wb.z, wb.w};
#pragma unroll
      for (int i = 0; i < 4; ++i)
#pragma unroll
        for (int c = 0; c < 8; ++c) acc[i][c] = fmaf(xv[i], wv[c], acc[i][c]);
    }
    __syncthreads();
  }

  float4 b0 = *reinterpret_cast<const float4*>(&bias[tx * 8]);
  float4 b1 = *reinterpret_cast<const float4*>(&bias[tx * 8 + 4]);
  float bv[8] = {b0.x, b0.y, b0.z, b0.w, b1.x, b1.y, b1.z, b1.w};
#pragma unroll
  for (int i = 0; i < 4; ++i) {
    int grow = row0 + ty * 4 + i;
    if (grow >= M) continue;
    float o[8];
#pragma unroll
    for (int c = 0; c < 8; ++c) o[c] = acc[i][c] + bv[c];
    *reinterpret_cast<float4*>(&out[(size_t)grow * 128 + tx * 8]) =
        make_float4(o[0], o[1], o[2], o[3]);
    *reinterpret_cast<float4*>(&out[(size_t)grow * 128 + tx * 8 + 4]) =
        make_float4(o[4], o[5], o[6], o[7]);
  }
}

// ------- update GEMM: X = concat(agg/cnt, base) (M x 256); + bias; LN; ReLU -------
__global__ __launch_bounds__(256) void gemm_upd(const float* __restrict__ agg,
                                                const float* __restrict__ cnt,
                                                const float* __restrict__ base,
                                                const float* __restrict__ Wt,
                                                const float* __restrict__ bias,
                                                const float* __restrict__ lng,
                                                const float* __restrict__ lnb,
                                                float* __restrict__ out, int M) {
  constexpr int K = 256, KK = 32;
  __shared__ float Xs[64][KK + 1];
  __shared__ float Ws[KK][128];
  const int tid = threadIdx.x;
  const int tx = tid & 15, ty = tid >> 4;
  const int row0 = blockIdx.x * 64;

  float acc[4][8];
#pragma unroll
  for (int i = 0; i < 4; ++i)
#pragma unroll
    for (int c = 0; c < 8; ++c) acc[i][c] = 0.f;

  for (int k0 = 0; k0 < K; k0 += KK) {
#pragma unroll
    for (int it = 0; it < 2; ++it) {
      int q = tid + it * 256;
      int r = q >> 3, kq = (q & 7) * 4;
      int grow = row0 + r, gk = k0 + kq;
      float4 v = make_float4(0.f, 0.f, 0.f, 0.f);
      if (grow < M) {
        if (gk < 128) {
          v = *reinterpret_cast<const float4*>(&agg[(size_t)grow * 128 + gk]);
          float ic = 1.0f / fmaxf(cnt[grow], 1.0f);
          v.x *= ic; v.y *= ic; v.z *= ic; v.w *= ic;
        } else {
          v = *reinterpret_cast<const float4*>(&base[(size_t)grow * 128 + (gk - 128)]);
        }
      }
      Xs[r][kq + 0] = v.x; Xs[r][kq + 1] = v.y; Xs[r][kq + 2] = v.z; Xs[r][kq + 3] = v.w;
    }
#pragma unroll
    for (int it = 0; it < 4; ++it) {
      int q = tid + it * 256;
      int kr = q >> 5, col = (q & 31) * 4;
      *reinterpret_cast<float4*>(&Ws[kr][col]) =
          *reinterpret_cast<const float4*>(&Wt[(size_t)(k0 + kr) * 128 + col]);
    }
    __syncthreads();
#pragma unroll
    for (int k = 0; k < KK; ++k) {
      float xv[4];
#pragma unroll
      for (int i = 0; i < 4; ++i) xv[i] = Xs[ty * 4 + i][k];
      float4 wa = *reinterpret_cast<const float4*>(&Ws[k][tx * 8]);
      float4 wb = *reinterpret_cast<const float4*>(&Ws[k][tx * 8 + 4]);
      float wv[8] = {wa.x, wa.y, wa.z, wa.w, wb.x, wb.y, wb.z, wb.w};
#pragma unroll
      for (int i = 0; i < 4; ++i)
#pragma unroll
        for (int c = 0; c < 8; ++c) acc[i][c] = fmaf(xv[i], wv[c], acc[i][c]);
    }
    __syncthreads();
  }

  // epilogue: bias + LayerNorm (over full 128-col row, held by the 16 tx lanes) + ReLU
  float4 b0 = *reinterpret_cast<const float4*>(&bias[tx * 8]);
  float4 b1 = *reinterpret_cast<const float4*>(&bias[tx * 8 + 4]);
  float bv[8] = {b0.x, b0.y, b0.z, b0.w, b1.x, b1.y, b1.z, b1.w};
  float4 g0 = *reinterpret_cast<const float4*>(&lng[tx * 8]);
  float4 g1 = *reinterpret_cast<const float4*>(&lng[tx * 8 + 4]);
  float gv[8] = {g0.x, g0.y, g0.z, g0.w, g1.x, g1.y, g1.z, g1.w};
  float4 l0 = *reinterpret_cast<const float4*>(&lnb[tx * 8]);
  float4 l1 = *reinterpret_cast<const float4*>(&lnb[tx * 8 + 4]);
  float lv[8] = {l0.x, l0.y, l0.z, l0.w, l1.x, l1.y, l1.z, l1.w};

#pragma unroll
  for (int i = 0; i < 4; ++i) {
    float z[8];
    float s = 0.f, sq = 0.f;
#pragma unroll
    for (int c = 0; c < 8; ++c) {
      z[c] = acc[i][c] + bv[c];
      s += z[c];
      sq += z[c] * z[c];
    }
#pragma unroll
    for (int m = 1; m < 16; m <<= 1) {
      s += __shfl_xor(s, m, 16);
      sq += __shfl_xor(sq, m, 16);
    }
    float mean = s * (1.f / 128.f);
    float var = sq * (1.f / 128.f) - mean * mean;
    float rstd = rsqrtf(var + LN_EPS);
    int grow = row0 + ty * 4 + i;
    if (grow < M) {
      float o[8];
#pragma unroll
      for (int c = 0; c < 8; ++c) {
        float y = (z[c] - mean) * rstd * gv[c] + lv[c];
        o[c] = fmaxf(y, 0.f);
      }
      *reinterpret_cast<float4*>(&out[(size_t)grow * 128 + tx * 8]) =
          make_float4(o[0], o[1], o[2], o[3]);
      *reinterpret_cast<float4*>(&out[(size_t)grow * 128 + tx * 8 + 4]) =
          make_float4(o[4], o[5], o[6], o[7]);
    }
  }
}

// ---------------- edge gather * gate -> atomic scatter-sum + count ----------------
__global__ __launch_bounds__(256) void edge_scatter(const int* __restrict__ gidx,
                                                    const int* __restrict__ sidx,
                                                    const float* __restrict__ ew,
                                                    const float* __restrict__ gw,
                                                    const float* __restrict__ gb,
                                                    const float* __restrict__ src,
                                                    float* __restrict__ agg,
                                                    float* __restrict__ cnt, int E) {
  long long t = (long long)blockIdx.x * 256 + threadIdx.x;
  int e = (int)(t >> 7);
  int j = (int)(t & 127);
  if (e >= E) return;
  int gi = gidx[e], si = sidx[e];
  float x = ew[e] * gw[j] + gb[j];
  float gate = 1.0f / (1.0f + __expf(-x));
  float val = src[(size_t)gi * 128 + j] * gate;
  atomicAdd(&agg[(size_t)si * 128 + j], val);
  if (j == 0) atomicAdd(&cnt[si], 1.0f);
}

extern "C" void kernel_launch(void* const* d_in, const int* in_sizes, int n_in,
                              void* d_out, int out_size, void* d_ws, size_t ws_size,
                              hipStream_t stream) {
  const float* vh = (const float*)d_in[0];
  const float* ch = (const float*)d_in[1];
  const int* ei = (const int*)d_in[2];   // [ci(E), vi(E)]
  const float* ew = (const float*)d_in[3];
  const float* v2c_lin_w = (const float*)d_in[4];
  const float* v2c_lin_b = (const float*)d_in[5];
  const float* v2c_gate_w = (const float*)d_in[6];
  const float* v2c_gate_b = (const float*)d_in[7];
  const float* v2c_upd_w = (const float*)d_in[8];
  const float* v2c_upd_b = (const float*)d_in[9];
  const float* v2c_ln_g = (const float*)d_in[10];
  const float* v2c_ln_b = (const float*)d_in[11];
  const float* c2v_lin_w = (const float*)d_in[12];
  const float* c2v_lin_b = (const float*)d_in[13];
  const float* c2v_gate_w = (const float*)d_in[14];
  const float* c2v_gate_b = (const float*)d_in[15];
  const float* c2v_upd_w = (const float*)d_in[16];
  const float* c2v_upd_b = (const float*)d_in[17];
  const float* c2v_ln_g = (const float*)d_in[18];
  const float* c2v_ln_b = (const float*)d_in[19];

  const int N = in_sizes[0] / 128;
  const int C = in_sizes[1] / 128;
  const int E = in_sizes[3];

  float* ws = (float*)d_ws;
  float* tmpNV = ws;                           // N*128 : tmp_v, later agg_v
  float* aggC = tmpNV + (size_t)N * 128;       // C*128 : agg_c, later tmp_c
  float* cntC = aggC + (size_t)C * 128;        // C
  float* cntV = cntC + C;                      // N
  float* wtLinV = cntV + N;                    // 128*128
  float* wtUpdV = wtLinV + 128 * 128;          // 256*128
  float* wtLinC = wtUpdV + 256 * 128;          // 128*128
  float* wtUpdC = wtLinC + 128 * 128;          // 256*128

  float* vhNew = (float*)d_out;
  float* chNew = (float*)d_out + (size_t)N * 128;

  dim3 tgrid(1, 128);
  transpose_w<<<tgrid, 256, 0, stream>>>(v2c_lin_w, wtLinV, 128);
  transpose_w<<<tgrid, 256, 0, stream>>>(v2c_upd_w, wtUpdV, 256);
  transpose_w<<<tgrid, 256, 0, stream>>>(c2v_lin_w, wtLinC, 128);
  transpose_w<<<tgrid, 256, 0, stream>>>(c2v_upd_w, wtUpdC, 256);

  // ---- v2c ----
  gemm_bias<128><<<(N + 63) / 64, 256, 0, stream>>>(vh, wtLinV, v2c_lin_b, tmpNV, N);
  hipMemsetAsync(aggC, 0, (size_t)C * 128 * sizeof(float), stream);
  hipMemsetAsync(cntC, 0, (size_t)C * sizeof(float), stream);
  {
    int grid = (int)(((long long)E * 128 + 255) / 256);
    edge_scatter<<<grid, 256, 0, stream>>>(ei + E, ei, ew, v2c_gate_w, v2c_gate_b,
                                           tmpNV, aggC, cntC, E);
  }
  gemm_upd<<<(C + 63) / 64, 256, 0, stream>>>(aggC, cntC, ch, wtUpdV, v2c_upd_b,
                                              v2c_ln_g, v2c_ln_b, chNew, C);

  // ---- c2v ----
  float* tmpC = aggC;  // reuse (agg_c dead after gemm_upd above)
  gemm_bias<128><<<(C + 63) / 64, 256, 0, stream>>>(chNew, wtLinC, c2v_lin_b, tmpC, C);
  float* aggV = tmpNV;  // reuse (tmp_v dead after first edge_scatter)
  hipMemsetAsync(aggV, 0, (size_t)N * 128 * sizeof(float), stream);
  hipMemsetAsync(cntV, 0, (size_t)N * sizeof(float), stream);
  {
    int grid = (int)(((long long)E * 128 + 255) / 256);
    edge_scatter<<<grid, 256, 0, stream>>>(ei, ei + E, ew, c2v_gate_w, c2v_gate_b,
                                           tmpC, aggV, cntV, E);
  }
  gemm_upd<<<(N + 63) / 64, 256, 0, stream>>>(aggV, cntV, vh, wtUpdC, c2v_upd_b,
                                              c2v_ln_g, c2v_ln_b, vhNew, N);
}

// Round 2
// 686.288 us; speedup vs baseline: 1.4332x; 1.4332x over previous
//
#include <hip/hip_runtime.h>

#define LN_EPS 1e-5f

// ---------------- transpose weight (N=128 rows, K cols) -> Wt (K x 128) ----
__global__ __launch_bounds__(256) void transpose_w(const float* __restrict__ in,
                                                   float* __restrict__ out, int K) {
  int n = blockIdx.y;                       // 0..127
  int k = blockIdx.x * 256 + threadIdx.x;   // 0..K-1
  if (k < K) out[(size_t)k * 128 + n] = in[(size_t)n * K + k];
}

// ---------------- counting sort: histogram ----------------
__global__ __launch_bounds__(256) void hist_kernel(const int* __restrict__ dest,
                                                   int* __restrict__ cnt, int E) {
  int e = blockIdx.x * 256 + threadIdx.x;
  if (e < E) atomicAdd(&cnt[dest[e]], 1);
}

// scan phase 1: 256 threads x 4 elems = 1024 per block; exclusive within block
__global__ __launch_bounds__(256) void scan1(const int* __restrict__ cnt,
                                             int* __restrict__ off,
                                             int* __restrict__ bsum, int M) {
  __shared__ int s[256];
  int base = blockIdx.x * 1024 + threadIdx.x * 4;
  int v[4];
  int tot = 0;
#pragma unroll
  for (int i = 0; i < 4; ++i) {
    int idx = base + i;
    v[i] = (idx < M) ? cnt[idx] : 0;
    tot += v[i];
  }
  s[threadIdx.x] = tot;
  __syncthreads();
  for (int d = 1; d < 256; d <<= 1) {
    int t = (threadIdx.x >= d) ? s[threadIdx.x - d] : 0;
    __syncthreads();
    s[threadIdx.x] += t;
    __syncthreads();
  }
  int excl = s[threadIdx.x] - tot;
#pragma unroll
  for (int i = 0; i < 4; ++i) {
    int idx = base + i;
    if (idx < M) off[idx] = excl;
    excl += v[i];
  }
  if (threadIdx.x == 255) bsum[blockIdx.x] = s[255];
}

// scan phase 2: single block, sequential chunks of 256, exclusive scan of bsum
__global__ __launch_bounds__(256) void scan2(int* __restrict__ bsum, int nb) {
  __shared__ int s[256];
  __shared__ int carry;
  if (threadIdx.x == 0) carry = 0;
  __syncthreads();
  for (int base = 0; base < nb; base += 256) {
    int idx = base + threadIdx.x;
    int v = (idx < nb) ? bsum[idx] : 0;
    s[threadIdx.x] = v;
    __syncthreads();
    for (int d = 1; d < 256; d <<= 1) {
      int t = (threadIdx.x >= d) ? s[threadIdx.x - d] : 0;
      __syncthreads();
      s[threadIdx.x] += t;
      __syncthreads();
    }
    if (idx < nb) bsum[idx] = s[threadIdx.x] - v + carry;
    __syncthreads();
    if (threadIdx.x == 0) carry += s[255];
    __syncthreads();
  }
}

// scan phase 3: add block offsets; set off[M] = E
__global__ __launch_bounds__(256) void scan3(int* __restrict__ off,
                                             const int* __restrict__ bsum, int M, int E) {
  int idx = blockIdx.x * 256 + threadIdx.x;
  if (idx < M) off[idx] += bsum[idx >> 10];
  if (idx == M) off[M] = E;
}

// reorder: eord[pos] = edge id, grouped by dest
__global__ __launch_bounds__(256) void reorder_kernel(const int* __restrict__ dest,
                                                      int* __restrict__ cursor,
                                                      int* __restrict__ eord, int E) {
  int e = blockIdx.x * 256 + threadIdx.x;
  if (e < E) {
    int p = atomicAdd(&cursor[dest[e]], 1);
    eord[p] = e;
  }
}

// ---------------- segmented gather*gate reduce -> mean ----------------
// one 64-thread block per destination row; lane j handles cols 2j, 2j+1
__global__ __launch_bounds__(64) void seg_reduce(const int* __restrict__ off,
                                                 const int* __restrict__ eord,
                                                 const int* __restrict__ gidx,
                                                 const float* __restrict__ ew,
                                                 const float* __restrict__ gw,
                                                 const float* __restrict__ gb,
                                                 const float* __restrict__ src,
                                                 float* __restrict__ out) {
  int c = blockIdx.x;
  int j = threadIdx.x;
  int start = off[c], end = off[c + 1];
  float gwa = gw[2 * j], gwb = gw[2 * j + 1];
  float gba = gb[2 * j], gbb = gb[2 * j + 1];
  float a0 = 0.f, a1 = 0.f;
  int p = start;
  for (; p + 2 <= end; p += 2) {
    int e0 = eord[p], e1 = eord[p + 1];
    int g0 = gidx[e0], g1 = gidx[e1];
    float w0 = ew[e0], w1 = ew[e1];
    float2 v0 = *reinterpret_cast<const float2*>(&src[(size_t)g0 * 128 + 2 * j]);
    float2 v1 = *reinterpret_cast<const float2*>(&src[(size_t)g1 * 128 + 2 * j]);
    float s0a = 1.f / (1.f + __expf(-(w0 * gwa + gba)));
    float s0b = 1.f / (1.f + __expf(-(w0 * gwb + gbb)));
    float s1a = 1.f / (1.f + __expf(-(w1 * gwa + gba)));
    float s1b = 1.f / (1.f + __expf(-(w1 * gwb + gbb)));
    a0 += v0.x * s0a + v1.x * s1a;
    a1 += v0.y * s0b + v1.y * s1b;
  }
  if (p < end) {
    int e0 = eord[p];
    int g0 = gidx[e0];
    float w0 = ew[e0];
    float2 v0 = *reinterpret_cast<const float2*>(&src[(size_t)g0 * 128 + 2 * j]);
    a0 += v0.x * (1.f / (1.f + __expf(-(w0 * gwa + gba))));
    a1 += v0.y * (1.f / (1.f + __expf(-(w0 * gwb + gbb))));
  }
  int cnt = end - start;
  float inv = 1.f / (float)(cnt > 1 ? cnt : 1);
  *reinterpret_cast<float2*>(&out[(size_t)c * 128 + 2 * j]) = make_float2(a0 * inv, a1 * inv);
}

// ---------------- out(M x 128) = X(M x K) @ Wt(K x 128) + bias ----------------
template <int K>
__global__ __launch_bounds__(256) void gemm_bias(const float* __restrict__ X,
                                                 const float* __restrict__ Wt,
                                                 const float* __restrict__ bias,
                                                 float* __restrict__ out, int M) {
  constexpr int KK = 32;
  __shared__ float Xs[64][KK + 1];
  __shared__ float Ws[KK][128];
  const int tid = threadIdx.x;
  const int tx = tid & 15, ty = tid >> 4;
  const int row0 = blockIdx.x * 64;

  float acc[4][8];
#pragma unroll
  for (int i = 0; i < 4; ++i)
#pragma unroll
    for (int c = 0; c < 8; ++c) acc[i][c] = 0.f;

  for (int k0 = 0; k0 < K; k0 += KK) {
#pragma unroll
    for (int it = 0; it < 2; ++it) {
      int q = tid + it * 256;
      int r = q >> 3, kq = (q & 7) * 4;
      float4 v = make_float4(0.f, 0.f, 0.f, 0.f);
      int grow = row0 + r;
      if (grow < M) v = *reinterpret_cast<const float4*>(&X[(size_t)grow * K + k0 + kq]);
      Xs[r][kq + 0] = v.x; Xs[r][kq + 1] = v.y; Xs[r][kq + 2] = v.z; Xs[r][kq + 3] = v.w;
    }
#pragma unroll
    for (int it = 0; it < 4; ++it) {
      int q = tid + it * 256;
      int kr = q >> 5, col = (q & 31) * 4;
      *reinterpret_cast<float4*>(&Ws[kr][col]) =
          *reinterpret_cast<const float4*>(&Wt[(size_t)(k0 + kr) * 128 + col]);
    }
    __syncthreads();
#pragma unroll
    for (int k = 0; k < KK; ++k) {
      float xv[4];
#pragma unroll
      for (int i = 0; i < 4; ++i) xv[i] = Xs[ty * 4 + i][k];
      float4 wa = *reinterpret_cast<const float4*>(&Ws[k][tx * 8]);
      float4 wb = *reinterpret_cast<const float4*>(&Ws[k][tx * 8 + 4]);
      float wv[8] = {wa.x, wa.y, wa.z, wa.w, wb.x, wb.y, wb.z, wb.w};
#pragma unroll
      for (int i = 0; i < 4; ++i)
#pragma unroll
        for (int c = 0; c < 8; ++c) acc[i][c] = fmaf(xv[i], wv[c], acc[i][c]);
    }
    __syncthreads();
  }

  float4 b0 = *reinterpret_cast<const float4*>(&bias[tx * 8]);
  float4 b1 = *reinterpret_cast<const float4*>(&bias[tx * 8 + 4]);
  float bv[8] = {b0.x, b0.y, b0.z, b0.w, b1.x, b1.y, b1.z, b1.w};
#pragma unroll
  for (int i = 0; i < 4; ++i) {
    int grow = row0 + ty * 4 + i;
    if (grow >= M) continue;
    float o[8];
#pragma unroll
    for (int c = 0; c < 8; ++c) o[c] = acc[i][c] + bv[c];
    *reinterpret_cast<float4*>(&out[(size_t)grow * 128 + tx * 8]) =
        make_float4(o[0], o[1], o[2], o[3]);
    *reinterpret_cast<float4*>(&out[(size_t)grow * 128 + tx * 8 + 4]) =
        make_float4(o[4], o[5], o[6], o[7]);
  }
}

// ------- update GEMM: X = concat(aggMean, base) (M x 256); + bias; LN; ReLU -------
__global__ __launch_bounds__(256) void gemm_upd(const float* __restrict__ agg,
                                                const float* __restrict__ base,
                                                const float* __restrict__ Wt,
                                                const float* __restrict__ bias,
                                                const float* __restrict__ lng,
                                                const float* __restrict__ lnb,
                                                float* __restrict__ out, int M) {
  constexpr int K = 256, KK = 32;
  __shared__ float Xs[64][KK + 1];
  __shared__ float Ws[KK][128];
  const int tid = threadIdx.x;
  const int tx = tid & 15, ty = tid >> 4;
  const int row0 = blockIdx.x * 64;

  float acc[4][8];
#pragma unroll
  for (int i = 0; i < 4; ++i)
#pragma unroll
    for (int c = 0; c < 8; ++c) acc[i][c] = 0.f;

  for (int k0 = 0; k0 < K; k0 += KK) {
#pragma unroll
    for (int it = 0; it < 2; ++it) {
      int q = tid + it * 256;
      int r = q >> 3, kq = (q & 7) * 4;
      int grow = row0 + r, gk = k0 + kq;
      float4 v = make_float4(0.f, 0.f, 0.f, 0.f);
      if (grow < M) {
        if (gk < 128) {
          v = *reinterpret_cast<const float4*>(&agg[(size_t)grow * 128 + gk]);
        } else {
          v = *reinterpret_cast<const float4*>(&base[(size_t)grow * 128 + (gk - 128)]);
        }
      }
      Xs[r][kq + 0] = v.x; Xs[r][kq + 1] = v.y; Xs[r][kq + 2] = v.z; Xs[r][kq + 3] = v.w;
    }
#pragma unroll
    for (int it = 0; it < 4; ++it) {
      int q = tid + it * 256;
      int kr = q >> 5, col = (q & 31) * 4;
      *reinterpret_cast<float4*>(&Ws[kr][col]) =
          *reinterpret_cast<const float4*>(&Wt[(size_t)(k0 + kr) * 128 + col]);
    }
    __syncthreads();
#pragma unroll
    for (int k = 0; k < KK; ++k) {
      float xv[4];
#pragma unroll
      for (int i = 0; i < 4; ++i) xv[i] = Xs[ty * 4 + i][k];
      float4 wa = *reinterpret_cast<const float4*>(&Ws[k][tx * 8]);
      float4 wb = *reinterpret_cast<const float4*>(&Ws[k][tx * 8 + 4]);
      float wv[8] = {wa.x, wa.y, wa.z, wa.w, wb.x, wb.y, wb.z, wb.w};
#pragma unroll
      for (int i = 0; i < 4; ++i)
#pragma unroll
        for (int c = 0; c < 8; ++c) acc[i][c] = fmaf(xv[i], wv[c], acc[i][c]);
    }
    __syncthreads();
  }

  float4 b0 = *reinterpret_cast<const float4*>(&bias[tx * 8]);
  float4 b1 = *reinterpret_cast<const float4*>(&bias[tx * 8 + 4]);
  float bv[8] = {b0.x, b0.y, b0.z, b0.w, b1.x, b1.y, b1.z, b1.w};
  float4 g0 = *reinterpret_cast<const float4*>(&lng[tx * 8]);
  float4 g1 = *reinterpret_cast<const float4*>(&lng[tx * 8 + 4]);
  float gv[8] = {g0.x, g0.y, g0.z, g0.w, g1.x, g1.y, g1.z, g1.w};
  float4 l0 = *reinterpret_cast<const float4*>(&lnb[tx * 8]);
  float4 l1 = *reinterpret_cast<const float4*>(&lnb[tx * 8 + 4]);
  float lv[8] = {l0.x, l0.y, l0.z, l0.w, l1.x, l1.y, l1.z, l1.w};

#pragma unroll
  for (int i = 0; i < 4; ++i) {
    float z[8];
    float s = 0.f, sq = 0.f;
#pragma unroll
    for (int c = 0; c < 8; ++c) {
      z[c] = acc[i][c] + bv[c];
      s += z[c];
      sq += z[c] * z[c];
    }
#pragma unroll
    for (int m = 1; m < 16; m <<= 1) {
      s += __shfl_xor(s, m, 16);
      sq += __shfl_xor(sq, m, 16);
    }
    float mean = s * (1.f / 128.f);
    float var = sq * (1.f / 128.f) - mean * mean;
    float rstd = rsqrtf(var + LN_EPS);
    int grow = row0 + ty * 4 + i;
    if (grow < M) {
      float o[8];
#pragma unroll
      for (int c = 0; c < 8; ++c) {
        float y = (z[c] - mean) * rstd * gv[c] + lv[c];
        o[c] = fmaxf(y, 0.f);
      }
      *reinterpret_cast<float4*>(&out[(size_t)grow * 128 + tx * 8]) =
          make_float4(o[0], o[1], o[2], o[3]);
      *reinterpret_cast<float4*>(&out[(size_t)grow * 128 + tx * 8 + 4]) =
          make_float4(o[4], o[5], o[6], o[7]);
    }
  }
}

extern "C" void kernel_launch(void* const* d_in, const int* in_sizes, int n_in,
                              void* d_out, int out_size, void* d_ws, size_t ws_size,
                              hipStream_t stream) {
  const float* vh = (const float*)d_in[0];
  const float* ch = (const float*)d_in[1];
  const int* ei = (const int*)d_in[2];   // [ci(E), vi(E)]
  const float* ew = (const float*)d_in[3];
  const float* v2c_lin_w = (const float*)d_in[4];
  const float* v2c_lin_b = (const float*)d_in[5];
  const float* v2c_gate_w = (const float*)d_in[6];
  const float* v2c_gate_b = (const float*)d_in[7];
  const float* v2c_upd_w = (const float*)d_in[8];
  const float* v2c_upd_b = (const float*)d_in[9];
  const float* v2c_ln_g = (const float*)d_in[10];
  const float* v2c_ln_b = (const float*)d_in[11];
  const float* c2v_lin_w = (const float*)d_in[12];
  const float* c2v_lin_b = (const float*)d_in[13];
  const float* c2v_gate_w = (const float*)d_in[14];
  const float* c2v_gate_b = (const float*)d_in[15];
  const float* c2v_upd_w = (const float*)d_in[16];
  const float* c2v_upd_b = (const float*)d_in[17];
  const float* c2v_ln_g = (const float*)d_in[18];
  const float* c2v_ln_b = (const float*)d_in[19];

  const int N = in_sizes[0] / 128;
  const int C = in_sizes[1] / 128;
  const int E = in_sizes[3];
  const int* ci = ei;
  const int* vi = ei + E;

  float* ws = (float*)d_ws;
  float* tmpNV = ws;                           // N*128 : tmp_v, later agg_v
  float* aggC = tmpNV + (size_t)N * 128;       // C*128 : agg_c, later tmp_c
  float* wtLinV = aggC + (size_t)C * 128;      // 128*128
  float* wtUpdV = wtLinV + 128 * 128;          // 256*128
  float* wtLinC = wtUpdV + 256 * 128;          // 128*128
  float* wtUpdC = wtLinC + 128 * 128;          // 256*128
  int* offC = (int*)(wtUpdC + 256 * 128);      // C+1
  int* offV = offC + (C + 1);                  // N+1
  int* eordC = offV + (N + 1);                 // E
  int* eordV = eordC + E;                      // E
  // sort scratch aliased into aggC region (dead until seg_reduce writes it)
  int* cntS = (int*)aggC;                      // max(C,N)
  int* curS = cntS + N;                        // max(C,N)
  int* bsumS = curS + N;                       // ~256

  float* vhNew = (float*)d_out;
  float* chNew = (float*)d_out + (size_t)N * 128;

  dim3 tgrid(1, 128);
  transpose_w<<<tgrid, 256, 0, stream>>>(v2c_lin_w, wtLinV, 128);
  transpose_w<<<tgrid, 256, 0, stream>>>(v2c_upd_w, wtUpdV, 256);
  transpose_w<<<tgrid, 256, 0, stream>>>(c2v_lin_w, wtLinC, 128);
  transpose_w<<<tgrid, 256, 0, stream>>>(c2v_upd_w, wtUpdC, 256);

  const int egrid = (E + 255) / 256;

  // ---- counting sort by ci (for v2c) ----
  hipMemsetAsync(cntS, 0, (size_t)C * sizeof(int), stream);
  hist_kernel<<<egrid, 256, 0, stream>>>(ci, cntS, E);
  {
    int nb = (C + 1023) / 1024;
    scan1<<<nb, 256, 0, stream>>>(cntS, offC, bsumS, C);
    scan2<<<1, 256, 0, stream>>>(bsumS, nb);
    scan3<<<(C + 1 + 255) / 256, 256, 0, stream>>>(offC, bsumS, C, E);
  }
  hipMemcpyAsync(curS, offC, (size_t)C * sizeof(int), hipMemcpyDeviceToDevice, stream);
  reorder_kernel<<<egrid, 256, 0, stream>>>(ci, curS, eordC, E);

  // ---- counting sort by vi (for c2v) ----
  hipMemsetAsync(cntS, 0, (size_t)N * sizeof(int), stream);
  hist_kernel<<<egrid, 256, 0, stream>>>(vi, cntS, E);
  {
    int nb = (N + 1023) / 1024;
    scan1<<<nb, 256, 0, stream>>>(cntS, offV, bsumS, N);
    scan2<<<1, 256, 0, stream>>>(bsumS, nb);
    scan3<<<(N + 1 + 255) / 256, 256, 0, stream>>>(offV, bsumS, N, E);
  }
  hipMemcpyAsync(curS, offV, (size_t)N * sizeof(int), hipMemcpyDeviceToDevice, stream);
  reorder_kernel<<<egrid, 256, 0, stream>>>(vi, curS, eordV, E);

  // ---- v2c ----
  gemm_bias<128><<<(N + 63) / 64, 256, 0, stream>>>(vh, wtLinV, v2c_lin_b, tmpNV, N);
  seg_reduce<<<C, 64, 0, stream>>>(offC, eordC, vi, ew, v2c_gate_w, v2c_gate_b,
                                   tmpNV, aggC);
  gemm_upd<<<(C + 63) / 64, 256, 0, stream>>>(aggC, ch, wtUpdV, v2c_upd_b,
                                              v2c_ln_g, v2c_ln_b, chNew, C);

  // ---- c2v ----
  float* tmpC = aggC;   // reuse (agg_c dead after gemm_upd)
  gemm_bias<128><<<(C + 63) / 64, 256, 0, stream>>>(chNew, wtLinC, c2v_lin_b, tmpC, C);
  float* aggV = tmpNV;  // reuse (tmp_v dead after v2c seg_reduce)
  seg_reduce<<<N, 64, 0, stream>>>(offV, eordV, ci, ew, c2v_gate_w, c2v_gate_b,
                                   tmpC, aggV);
  gemm_upd<<<(N + 63) / 64, 256, 0, stream>>>(aggV, vh, wtUpdC, c2v_upd_b,
                                              c2v_ln_g, c2v_ln_b, vhNew, N);
}

// Round 3
// 424.553 us; speedup vs baseline: 2.3168x; 1.6165x over previous
//
#include <hip/hip_runtime.h>

#define LN_EPS 1e-5f

typedef float f32x4 __attribute__((ext_vector_type(4)));
typedef short bf16x8 __attribute__((ext_vector_type(8)));
typedef unsigned short u16x4 __attribute__((ext_vector_type(4)));

__device__ __forceinline__ unsigned short f2bf(float f) {
  unsigned int u = __float_as_uint(f);
  u = (u + 0x7fffu + ((u >> 16) & 1u)) >> 16;
  return (unsigned short)u;
}
__device__ __forceinline__ float bf2f(unsigned short h) {
  return __uint_as_float((unsigned int)h << 16);
}

// ---------------- f32 -> bf16 convert (weights) ----------------
__global__ __launch_bounds__(256) void cvt_bf16(const float* __restrict__ in,
                                                unsigned short* __restrict__ out, int n) {
  int i = blockIdx.x * 256 + threadIdx.x;
  if (i < n) out[i] = f2bf(in[i]);
}

// ---------------- counting sort: histogram ----------------
__global__ __launch_bounds__(256) void hist_kernel(const int* __restrict__ dest,
                                                   int* __restrict__ cnt, int E) {
  int e = blockIdx.x * 256 + threadIdx.x;
  if (e < E) atomicAdd(&cnt[dest[e]], 1);
}

__global__ __launch_bounds__(256) void scan1(const int* __restrict__ cnt,
                                             int* __restrict__ off,
                                             int* __restrict__ bsum, int M) {
  __shared__ int s[256];
  int base = blockIdx.x * 1024 + threadIdx.x * 4;
  int v[4];
  int tot = 0;
#pragma unroll
  for (int i = 0; i < 4; ++i) {
    int idx = base + i;
    v[i] = (idx < M) ? cnt[idx] : 0;
    tot += v[i];
  }
  s[threadIdx.x] = tot;
  __syncthreads();
  for (int d = 1; d < 256; d <<= 1) {
    int t = (threadIdx.x >= d) ? s[threadIdx.x - d] : 0;
    __syncthreads();
    s[threadIdx.x] += t;
    __syncthreads();
  }
  int excl = s[threadIdx.x] - tot;
#pragma unroll
  for (int i = 0; i < 4; ++i) {
    int idx = base + i;
    if (idx < M) off[idx] = excl;
    excl += v[i];
  }
  if (threadIdx.x == 255) bsum[blockIdx.x] = s[255];
}

__global__ __launch_bounds__(256) void scan2(int* __restrict__ bsum, int nb) {
  __shared__ int s[256];
  __shared__ int carry;
  if (threadIdx.x == 0) carry = 0;
  __syncthreads();
  for (int base = 0; base < nb; base += 256) {
    int idx = base + threadIdx.x;
    int v = (idx < nb) ? bsum[idx] : 0;
    s[threadIdx.x] = v;
    __syncthreads();
    for (int d = 1; d < 256; d <<= 1) {
      int t = (threadIdx.x >= d) ? s[threadIdx.x - d] : 0;
      __syncthreads();
      s[threadIdx.x] += t;
      __syncthreads();
    }
    if (idx < nb) bsum[idx] = s[threadIdx.x] - v + carry;
    __syncthreads();
    if (threadIdx.x == 0) carry += s[255];
    __syncthreads();
  }
}

__global__ __launch_bounds__(256) void scan3(int* __restrict__ off,
                                             const int* __restrict__ bsum, int M, int E) {
  int idx = blockIdx.x * 256 + threadIdx.x;
  if (idx < M) off[idx] += bsum[idx >> 10];
  if (idx == M) off[M] = E;
}

__global__ __launch_bounds__(256) void reorder_kernel(const int* __restrict__ dest,
                                                      int* __restrict__ cursor,
                                                      int* __restrict__ eord, int E) {
  int e = blockIdx.x * 256 + threadIdx.x;
  if (e < E) {
    int p = atomicAdd(&cursor[dest[e]], 1);
    eord[p] = e;
  }
}

// ---------------- segmented gather*gate reduce -> mean (bf16 src/out) ----------------
__global__ __launch_bounds__(64) void seg_reduce(const int* __restrict__ off,
                                                 const int* __restrict__ eord,
                                                 const int* __restrict__ gidx,
                                                 const float* __restrict__ ew,
                                                 const float* __restrict__ gw,
                                                 const float* __restrict__ gb,
                                                 const unsigned short* __restrict__ src,
                                                 unsigned short* __restrict__ out) {
  int c = blockIdx.x;
  int j = threadIdx.x;
  int start = off[c], end = off[c + 1];
  float gwa = gw[2 * j], gwb = gw[2 * j + 1];
  float gba = gb[2 * j], gbb = gb[2 * j + 1];
  float a0 = 0.f, a1 = 0.f;
  int p = start;
  for (; p + 2 <= end; p += 2) {
    int e0 = eord[p], e1 = eord[p + 1];
    int g0 = gidx[e0], g1 = gidx[e1];
    float w0 = ew[e0], w1 = ew[e1];
    unsigned int v0 = *reinterpret_cast<const unsigned int*>(&src[(size_t)g0 * 128 + 2 * j]);
    unsigned int v1 = *reinterpret_cast<const unsigned int*>(&src[(size_t)g1 * 128 + 2 * j]);
    float s0a = 1.f / (1.f + __expf(-(w0 * gwa + gba)));
    float s0b = 1.f / (1.f + __expf(-(w0 * gwb + gbb)));
    float s1a = 1.f / (1.f + __expf(-(w1 * gwa + gba)));
    float s1b = 1.f / (1.f + __expf(-(w1 * gwb + gbb)));
    a0 += bf2f((unsigned short)(v0 & 0xffff)) * s0a + bf2f((unsigned short)(v1 & 0xffff)) * s1a;
    a1 += bf2f((unsigned short)(v0 >> 16)) * s0b + bf2f((unsigned short)(v1 >> 16)) * s1b;
  }
  if (p < end) {
    int e0 = eord[p];
    int g0 = gidx[e0];
    float w0 = ew[e0];
    unsigned int v0 = *reinterpret_cast<const unsigned int*>(&src[(size_t)g0 * 128 + 2 * j]);
    a0 += bf2f((unsigned short)(v0 & 0xffff)) * (1.f / (1.f + __expf(-(w0 * gwa + gba))));
    a1 += bf2f((unsigned short)(v0 >> 16)) * (1.f / (1.f + __expf(-(w0 * gwb + gbb))));
  }
  int cnt = end - start;
  float inv = 1.f / (float)(cnt > 1 ? cnt : 1);
  unsigned int packed = (unsigned int)f2bf(a0 * inv) | ((unsigned int)f2bf(a1 * inv) << 16);
  *reinterpret_cast<unsigned int*>(&out[(size_t)c * 128 + 2 * j]) = packed;
}

// ------- MFMA GEMM: out(M x 128) bf16 = bf16(X f32) @ Wbf^T + bias -------
// W native layout w[n][k] IS the B-fragment layout (k contiguous per out-col).
template <int K>
__global__ __launch_bounds__(256) void gemm_lin_mfma(const float* __restrict__ X,
                                                     const unsigned short* __restrict__ Wbf,
                                                     const float* __restrict__ bias,
                                                     unsigned short* __restrict__ out, int M) {
  __shared__ unsigned short Xs[64][40];   // 80B row stride: conflict-free b128 reads
  __shared__ unsigned short Bs[128][40];
  const int tid = threadIdx.x;
  const int lane = tid & 63, wv = tid >> 6;
  const int lr = lane & 15, lg = lane >> 4;
  const int row0 = blockIdx.x * 64;

  f32x4 acc[4][2];
#pragma unroll
  for (int mf = 0; mf < 4; ++mf)
#pragma unroll
    for (int nf = 0; nf < 2; ++nf) acc[mf][nf] = (f32x4)(0.f);

  for (int k0 = 0; k0 < K; k0 += 32) {
#pragma unroll
    for (int it = 0; it < 2; ++it) {
      int q = tid + it * 256;             // [0,512): 4 elems each of 64x32 X tile
      int r = q >> 3, kq = (q & 7) * 4;
      int grow = row0 + r;
      float4 v = make_float4(0.f, 0.f, 0.f, 0.f);
      if (grow < M) v = *reinterpret_cast<const float4*>(&X[(size_t)grow * K + k0 + kq]);
      u16x4 p = {f2bf(v.x), f2bf(v.y), f2bf(v.z), f2bf(v.w)};
      *reinterpret_cast<u16x4*>(&Xs[r][kq]) = p;
    }
#pragma unroll
    for (int it = 0; it < 2; ++it) {
      int q = tid + it * 256;             // [0,512): 8 elems each of 128x32 W tile
      int n = q >> 2, kq = (q & 3) * 8;
      bf16x8 wrow = *reinterpret_cast<const bf16x8*>(&Wbf[(size_t)n * K + k0 + kq]);
      *reinterpret_cast<bf16x8*>(&Bs[n][kq]) = wrow;
    }
    __syncthreads();
    bf16x8 a[4], b[2];
#pragma unroll
    for (int mf = 0; mf < 4; ++mf)
      a[mf] = *reinterpret_cast<const bf16x8*>(&Xs[mf * 16 + lr][lg * 8]);
#pragma unroll
    for (int nf = 0; nf < 2; ++nf)
      b[nf] = *reinterpret_cast<const bf16x8*>(&Bs[wv * 32 + nf * 16 + lr][lg * 8]);
#pragma unroll
    for (int mf = 0; mf < 4; ++mf)
#pragma unroll
      for (int nf = 0; nf < 2; ++nf)
        acc[mf][nf] = __builtin_amdgcn_mfma_f32_16x16x32_bf16(a[mf], b[nf], acc[mf][nf], 0, 0, 0);
    __syncthreads();
  }

  int col[2];
  float bv[2];
#pragma unroll
  for (int nf = 0; nf < 2; ++nf) {
    col[nf] = wv * 32 + nf * 16 + lr;
    bv[nf] = bias[col[nf]];
  }
#pragma unroll
  for (int mf = 0; mf < 4; ++mf)
#pragma unroll
    for (int reg = 0; reg < 4; ++reg) {
      int grow = row0 + mf * 16 + lg * 4 + reg;
      if (grow < M) {
#pragma unroll
        for (int nf = 0; nf < 2; ++nf)
          out[(size_t)grow * 128 + col[nf]] = f2bf(acc[mf][nf][reg] + bv[nf]);
      }
    }
}

// ------- MFMA update GEMM: X = concat(agg bf16, base f32) (M x 256); LN; ReLU -------
__global__ __launch_bounds__(256) void gemm_upd_mfma(const unsigned short* __restrict__ agg,
                                                     const float* __restrict__ base,
                                                     const unsigned short* __restrict__ Wbf,
                                                     const float* __restrict__ bias,
                                                     const float* __restrict__ lng,
                                                     const float* __restrict__ lnb,
                                                     float* __restrict__ out, int M) {
  constexpr int K = 256;
  __shared__ unsigned short Xs[64][40];
  __shared__ unsigned short Bs[128][40];
  __shared__ float sredS[64][4];
  __shared__ float sredQ[64][4];
  const int tid = threadIdx.x;
  const int lane = tid & 63, wv = tid >> 6;
  const int lr = lane & 15, lg = lane >> 4;
  const int row0 = blockIdx.x * 64;

  f32x4 acc[4][2];
#pragma unroll
  for (int mf = 0; mf < 4; ++mf)
#pragma unroll
    for (int nf = 0; nf < 2; ++nf) acc[mf][nf] = (f32x4)(0.f);

  for (int k0 = 0; k0 < K; k0 += 32) {
#pragma unroll
    for (int it = 0; it < 2; ++it) {
      int q = tid + it * 256;
      int r = q >> 3, kq = (q & 7) * 4;
      int grow = row0 + r, gk = k0 + kq;
      u16x4 p = {0, 0, 0, 0};
      if (grow < M) {
        if (gk < 128) {
          p = *reinterpret_cast<const u16x4*>(&agg[(size_t)grow * 128 + gk]);
        } else {
          float4 v = *reinterpret_cast<const float4*>(&base[(size_t)grow * 128 + (gk - 128)]);
          p = {f2bf(v.x), f2bf(v.y), f2bf(v.z), f2bf(v.w)};
        }
      }
      *reinterpret_cast<u16x4*>(&Xs[r][kq]) = p;
    }
#pragma unroll
    for (int it = 0; it < 2; ++it) {
      int q = tid + it * 256;
      int n = q >> 2, kq = (q & 3) * 8;
      bf16x8 wrow = *reinterpret_cast<const bf16x8*>(&Wbf[(size_t)n * K + k0 + kq]);
      *reinterpret_cast<bf16x8*>(&Bs[n][kq]) = wrow;
    }
    __syncthreads();
    bf16x8 a[4], b[2];
#pragma unroll
    for (int mf = 0; mf < 4; ++mf)
      a[mf] = *reinterpret_cast<const bf16x8*>(&Xs[mf * 16 + lr][lg * 8]);
#pragma unroll
    for (int nf = 0; nf < 2; ++nf)
      b[nf] = *reinterpret_cast<const bf16x8*>(&Bs[wv * 32 + nf * 16 + lr][lg * 8]);
#pragma unroll
    for (int mf = 0; mf < 4; ++mf)
#pragma unroll
      for (int nf = 0; nf < 2; ++nf)
        acc[mf][nf] = __builtin_amdgcn_mfma_f32_16x16x32_bf16(a[mf], b[nf], acc[mf][nf], 0, 0, 0);
    __syncthreads();
  }

  int col[2];
  float bv[2], gv[2], lv[2];
#pragma unroll
  for (int nf = 0; nf < 2; ++nf) {
    col[nf] = wv * 32 + nf * 16 + lr;
    bv[nf] = bias[col[nf]];
    gv[nf] = lng[col[nf]];
    lv[nf] = lnb[col[nf]];
  }

  float z[4][4][2];
#pragma unroll
  for (int mf = 0; mf < 4; ++mf)
#pragma unroll
    for (int reg = 0; reg < 4; ++reg) {
      float z0 = acc[mf][0][reg] + bv[0];
      float z1 = acc[mf][1][reg] + bv[1];
      z[mf][reg][0] = z0;
      z[mf][reg][1] = z1;
      float s = z0 + z1;
      float q = z0 * z0 + z1 * z1;
#pragma unroll
      for (int m = 1; m < 16; m <<= 1) {
        s += __shfl_xor(s, m);
        q += __shfl_xor(q, m);
      }
      if (lr == 0) {
        sredS[mf * 16 + lg * 4 + reg][wv] = s;
        sredQ[mf * 16 + lg * 4 + reg][wv] = q;
      }
    }
  __syncthreads();
#pragma unroll
  for (int mf = 0; mf < 4; ++mf)
#pragma unroll
    for (int reg = 0; reg < 4; ++reg) {
      int tr = mf * 16 + lg * 4 + reg;
      f32x4 S4 = *reinterpret_cast<const f32x4*>(&sredS[tr][0]);
      f32x4 Q4 = *reinterpret_cast<const f32x4*>(&sredQ[tr][0]);
      float S = S4[0] + S4[1] + S4[2] + S4[3];
      float Q = Q4[0] + Q4[1] + Q4[2] + Q4[3];
      float mean = S * (1.f / 128.f);
      float var = Q * (1.f / 128.f) - mean * mean;
      float rstd = rsqrtf(var + LN_EPS);
      int grow = row0 + tr;
      if (grow < M) {
#pragma unroll
        for (int nf = 0; nf < 2; ++nf) {
          float y = (z[mf][reg][nf] - mean) * rstd * gv[nf] + lv[nf];
          out[(size_t)grow * 128 + col[nf]] = fmaxf(y, 0.f);
        }
      }
    }
}

extern "C" void kernel_launch(void* const* d_in, const int* in_sizes, int n_in,
                              void* d_out, int out_size, void* d_ws, size_t ws_size,
                              hipStream_t stream) {
  const float* vh = (const float*)d_in[0];
  const float* ch = (const float*)d_in[1];
  const int* ei = (const int*)d_in[2];   // [ci(E), vi(E)]
  const float* ew = (const float*)d_in[3];
  const float* v2c_lin_w = (const float*)d_in[4];
  const float* v2c_lin_b = (const float*)d_in[5];
  const float* v2c_gate_w = (const float*)d_in[6];
  const float* v2c_gate_b = (const float*)d_in[7];
  const float* v2c_upd_w = (const float*)d_in[8];
  const float* v2c_upd_b = (const float*)d_in[9];
  const float* v2c_ln_g = (const float*)d_in[10];
  const float* v2c_ln_b = (const float*)d_in[11];
  const float* c2v_lin_w = (const float*)d_in[12];
  const float* c2v_lin_b = (const float*)d_in[13];
  const float* c2v_gate_w = (const float*)d_in[14];
  const float* c2v_gate_b = (const float*)d_in[15];
  const float* c2v_upd_w = (const float*)d_in[16];
  const float* c2v_upd_b = (const float*)d_in[17];
  const float* c2v_ln_g = (const float*)d_in[18];
  const float* c2v_ln_b = (const float*)d_in[19];

  const int N = in_sizes[0] / 128;
  const int C = in_sizes[1] / 128;
  const int E = in_sizes[3];
  const int* ci = ei;
  const int* vi = ei + E;

  unsigned short* tmpNV = (unsigned short*)d_ws;        // N*128 bf16: tmp_v, later agg_v
  unsigned short* aggC = tmpNV + (size_t)N * 128;       // C*128 bf16: agg_c, later tmp_c
  unsigned short* wbfLinV = aggC + (size_t)C * 128;     // 128*128
  unsigned short* wbfUpdV = wbfLinV + 128 * 128;        // 128*256
  unsigned short* wbfLinC = wbfUpdV + 128 * 256;        // 128*128
  unsigned short* wbfUpdC = wbfLinC + 128 * 128;        // 128*256
  int* offC = (int*)(wbfUpdC + 128 * 256);              // C+1
  int* offV = offC + (C + 1);                           // N+1
  int* eordC = offV + (N + 1);                          // E
  int* eordV = eordC + E;                               // E
  // sort scratch aliased into aggC region (dead until seg_reduce writes it)
  int* cntS = (int*)aggC;                               // max(C,N)
  int* curS = cntS + N;                                 // max(C,N)
  int* bsumS = curS + N;                                // ~256

  float* vhNew = (float*)d_out;
  float* chNew = (float*)d_out + (size_t)N * 128;

  // weight f32->bf16
  cvt_bf16<<<(128 * 128 + 255) / 256, 256, 0, stream>>>(v2c_lin_w, wbfLinV, 128 * 128);
  cvt_bf16<<<(128 * 256 + 255) / 256, 256, 0, stream>>>(v2c_upd_w, wbfUpdV, 128 * 256);
  cvt_bf16<<<(128 * 128 + 255) / 256, 256, 0, stream>>>(c2v_lin_w, wbfLinC, 128 * 128);
  cvt_bf16<<<(128 * 256 + 255) / 256, 256, 0, stream>>>(c2v_upd_w, wbfUpdC, 128 * 256);

  const int egrid = (E + 255) / 256;

  // ---- counting sort by ci (for v2c) ----
  hipMemsetAsync(cntS, 0, (size_t)C * sizeof(int), stream);
  hist_kernel<<<egrid, 256, 0, stream>>>(ci, cntS, E);
  {
    int nb = (C + 1023) / 1024;
    scan1<<<nb, 256, 0, stream>>>(cntS, offC, bsumS, C);
    scan2<<<1, 256, 0, stream>>>(bsumS, nb);
    scan3<<<(C + 1 + 255) / 256, 256, 0, stream>>>(offC, bsumS, C, E);
  }
  hipMemcpyAsync(curS, offC, (size_t)C * sizeof(int), hipMemcpyDeviceToDevice, stream);
  reorder_kernel<<<egrid, 256, 0, stream>>>(ci, curS, eordC, E);

  // ---- counting sort by vi (for c2v) ----
  hipMemsetAsync(cntS, 0, (size_t)N * sizeof(int), stream);
  hist_kernel<<<egrid, 256, 0, stream>>>(vi, cntS, E);
  {
    int nb = (N + 1023) / 1024;
    scan1<<<nb, 256, 0, stream>>>(cntS, offV, bsumS, N);
    scan2<<<1, 256, 0, stream>>>(bsumS, nb);
    scan3<<<(N + 1 + 255) / 256, 256, 0, stream>>>(offV, bsumS, N, E);
  }
  hipMemcpyAsync(curS, offV, (size_t)N * sizeof(int), hipMemcpyDeviceToDevice, stream);
  reorder_kernel<<<egrid, 256, 0, stream>>>(vi, curS, eordV, E);

  // ---- v2c ----
  gemm_lin_mfma<128><<<(N + 63) / 64, 256, 0, stream>>>(vh, wbfLinV, v2c_lin_b, tmpNV, N);
  seg_reduce<<<C, 64, 0, stream>>>(offC, eordC, vi, ew, v2c_gate_w, v2c_gate_b,
                                   tmpNV, aggC);
  gemm_upd_mfma<<<(C + 63) / 64, 256, 0, stream>>>(aggC, ch, wbfUpdV, v2c_upd_b,
                                                   v2c_ln_g, v2c_ln_b, chNew, C);

  // ---- c2v ----
  unsigned short* tmpC = aggC;   // reuse (agg_c dead after gemm_upd)
  gemm_lin_mfma<128><<<(C + 63) / 64, 256, 0, stream>>>(chNew, wbfLinC, c2v_lin_b, tmpC, C);
  unsigned short* aggV = tmpNV;  // reuse (tmp_v dead after v2c seg_reduce)
  seg_reduce<<<N, 64, 0, stream>>>(offV, eordV, ci, ew, c2v_gate_w, c2v_gate_b,
                                   tmpC, aggV);
  gemm_upd_mfma<<<(N + 63) / 64, 256, 0, stream>>>(aggV, vh, wbfUpdC, c2v_upd_b,
                                                   c2v_ln_g, c2v_ln_b, vhNew, N);
}

// Round 4
// 398.470 us; speedup vs baseline: 2.4685x; 1.0655x over previous
//
#include <hip/hip_runtime.h>

#define LN_EPS 1e-5f

typedef float f32x4 __attribute__((ext_vector_type(4)));
typedef short bf16x8 __attribute__((ext_vector_type(8)));
typedef unsigned short u16x4 __attribute__((ext_vector_type(4)));

__device__ __forceinline__ unsigned short f2bf(float f) {
  unsigned int u = __float_as_uint(f);
  u = (u + 0x7fffu + ((u >> 16) & 1u)) >> 16;
  return (unsigned short)u;
}
__device__ __forceinline__ float bf2f(unsigned short h) {
  return __uint_as_float((unsigned int)h << 16);
}
__device__ __forceinline__ float sigm(float x) {
  return 1.f / (1.f + __expf(-x));
}

// ---------------- f32 -> bf16 convert (weights) ----------------
__global__ __launch_bounds__(256) void cvt_bf16(const float* __restrict__ in,
                                                unsigned short* __restrict__ out, int n) {
  int i = blockIdx.x * 256 + threadIdx.x;
  if (i < n) out[i] = f2bf(in[i]);
}

// ---------------- counting sort: histogram ----------------
__global__ __launch_bounds__(256) void hist_kernel(const int* __restrict__ dest,
                                                   int* __restrict__ cnt, int E) {
  int e = blockIdx.x * 256 + threadIdx.x;
  if (e < E) atomicAdd(&cnt[dest[e]], 1);
}

__global__ __launch_bounds__(256) void scan1(const int* __restrict__ cnt,
                                             int* __restrict__ off,
                                             int* __restrict__ bsum, int M) {
  __shared__ int s[256];
  int base = blockIdx.x * 1024 + threadIdx.x * 4;
  int v[4];
  int tot = 0;
#pragma unroll
  for (int i = 0; i < 4; ++i) {
    int idx = base + i;
    v[i] = (idx < M) ? cnt[idx] : 0;
    tot += v[i];
  }
  s[threadIdx.x] = tot;
  __syncthreads();
  for (int d = 1; d < 256; d <<= 1) {
    int t = (threadIdx.x >= d) ? s[threadIdx.x - d] : 0;
    __syncthreads();
    s[threadIdx.x] += t;
    __syncthreads();
  }
  int excl = s[threadIdx.x] - tot;
#pragma unroll
  for (int i = 0; i < 4; ++i) {
    int idx = base + i;
    if (idx < M) off[idx] = excl;
    excl += v[i];
  }
  if (threadIdx.x == 255) bsum[blockIdx.x] = s[255];
}

__global__ __launch_bounds__(256) void scan2(int* __restrict__ bsum, int nb) {
  __shared__ int s[256];
  __shared__ int carry;
  if (threadIdx.x == 0) carry = 0;
  __syncthreads();
  for (int base = 0; base < nb; base += 256) {
    int idx = base + threadIdx.x;
    int v = (idx < nb) ? bsum[idx] : 0;
    s[threadIdx.x] = v;
    __syncthreads();
    for (int d = 1; d < 256; d <<= 1) {
      int t = (threadIdx.x >= d) ? s[threadIdx.x - d] : 0;
      __syncthreads();
      s[threadIdx.x] += t;
      __syncthreads();
    }
    if (idx < nb) bsum[idx] = s[threadIdx.x] - v + carry;
    __syncthreads();
    if (threadIdx.x == 0) carry += s[255];
    __syncthreads();
  }
}

__global__ __launch_bounds__(256) void scan3(int* __restrict__ off,
                                             const int* __restrict__ bsum, int M, int E) {
  int idx = blockIdx.x * 256 + threadIdx.x;
  if (idx < M) off[idx] += bsum[idx >> 10];
  if (idx == M) off[M] = E;
}

// reorder: edata[pos] = {gather index, ew bits}, grouped by dest
__global__ __launch_bounds__(256) void reorder_kernel(const int* __restrict__ dest,
                                                      const int* __restrict__ gsrc,
                                                      const float* __restrict__ ew,
                                                      int* __restrict__ cursor,
                                                      int2* __restrict__ edata, int E) {
  int e = blockIdx.x * 256 + threadIdx.x;
  if (e < E) {
    int p = atomicAdd(&cursor[dest[e]], 1);
    edata[p] = make_int2(gsrc[e], __float_as_int(ew[e]));
  }
}

// ---------------- segmented gather*gate reduce -> mean (bf16 src/out) ----------------
// 256-thread block = 4 waves; wave w handles segment blockIdx.x*4+w; lane j: cols 2j,2j+1
__global__ __launch_bounds__(256) void seg_reduce(const int* __restrict__ off,
                                                  const int2* __restrict__ edata,
                                                  const float* __restrict__ gw,
                                                  const float* __restrict__ gb,
                                                  const unsigned short* __restrict__ src,
                                                  unsigned short* __restrict__ out, int M) {
  int seg = blockIdx.x * 4 + (threadIdx.x >> 6);
  if (seg >= M) return;
  int j = threadIdx.x & 63;
  int start = off[seg], end = off[seg + 1];
  float gwa = gw[2 * j], gwb = gw[2 * j + 1];
  float gba = gb[2 * j], gbb = gb[2 * j + 1];
  float a0 = 0.f, a1 = 0.f;
  int p = start;
  for (; p + 4 <= end; p += 4) {
    int2 e0 = edata[p], e1 = edata[p + 1], e2 = edata[p + 2], e3 = edata[p + 3];
    unsigned int v0 = *reinterpret_cast<const unsigned int*>(&src[(size_t)e0.x * 128 + 2 * j]);
    unsigned int v1 = *reinterpret_cast<const unsigned int*>(&src[(size_t)e1.x * 128 + 2 * j]);
    unsigned int v2 = *reinterpret_cast<const unsigned int*>(&src[(size_t)e2.x * 128 + 2 * j]);
    unsigned int v3 = *reinterpret_cast<const unsigned int*>(&src[(size_t)e3.x * 128 + 2 * j]);
    float w0 = __int_as_float(e0.y), w1 = __int_as_float(e1.y);
    float w2 = __int_as_float(e2.y), w3 = __int_as_float(e3.y);
    a0 += bf2f((unsigned short)(v0 & 0xffff)) * sigm(w0 * gwa + gba)
        + bf2f((unsigned short)(v1 & 0xffff)) * sigm(w1 * gwa + gba)
        + bf2f((unsigned short)(v2 & 0xffff)) * sigm(w2 * gwa + gba)
        + bf2f((unsigned short)(v3 & 0xffff)) * sigm(w3 * gwa + gba);
    a1 += bf2f((unsigned short)(v0 >> 16)) * sigm(w0 * gwb + gbb)
        + bf2f((unsigned short)(v1 >> 16)) * sigm(w1 * gwb + gbb)
        + bf2f((unsigned short)(v2 >> 16)) * sigm(w2 * gwb + gbb)
        + bf2f((unsigned short)(v3 >> 16)) * sigm(w3 * gwb + gbb);
  }
  if (p + 2 <= end) {
    int2 e0 = edata[p], e1 = edata[p + 1];
    unsigned int v0 = *reinterpret_cast<const unsigned int*>(&src[(size_t)e0.x * 128 + 2 * j]);
    unsigned int v1 = *reinterpret_cast<const unsigned int*>(&src[(size_t)e1.x * 128 + 2 * j]);
    float w0 = __int_as_float(e0.y), w1 = __int_as_float(e1.y);
    a0 += bf2f((unsigned short)(v0 & 0xffff)) * sigm(w0 * gwa + gba)
        + bf2f((unsigned short)(v1 & 0xffff)) * sigm(w1 * gwa + gba);
    a1 += bf2f((unsigned short)(v0 >> 16)) * sigm(w0 * gwb + gbb)
        + bf2f((unsigned short)(v1 >> 16)) * sigm(w1 * gwb + gbb);
    p += 2;
  }
  if (p < end) {
    int2 e0 = edata[p];
    unsigned int v0 = *reinterpret_cast<const unsigned int*>(&src[(size_t)e0.x * 128 + 2 * j]);
    float w0 = __int_as_float(e0.y);
    a0 += bf2f((unsigned short)(v0 & 0xffff)) * sigm(w0 * gwa + gba);
    a1 += bf2f((unsigned short)(v0 >> 16)) * sigm(w0 * gwb + gbb);
  }
  int cnt = end - start;
  float inv = 1.f / (float)(cnt > 1 ? cnt : 1);
  unsigned int packed = (unsigned int)f2bf(a0 * inv) | ((unsigned int)f2bf(a1 * inv) << 16);
  *reinterpret_cast<unsigned int*>(&out[(size_t)seg * 128 + 2 * j]) = packed;
}

// ------- MFMA GEMM: out(M x 128) bf16 = bf16(X f32) @ Wbf^T + bias -------
template <int K>
__global__ __launch_bounds__(256) void gemm_lin_mfma(const float* __restrict__ X,
                                                     const unsigned short* __restrict__ Wbf,
                                                     const float* __restrict__ bias,
                                                     unsigned short* __restrict__ out, int M) {
  __shared__ unsigned short Xs[64][40];   // 80B row stride: conflict-free b128 reads
  __shared__ unsigned short Bs[128][40];
  const int tid = threadIdx.x;
  const int lane = tid & 63, wv = tid >> 6;
  const int lr = lane & 15, lg = lane >> 4;
  const int row0 = blockIdx.x * 64;

  f32x4 acc[4][2];
#pragma unroll
  for (int mf = 0; mf < 4; ++mf)
#pragma unroll
    for (int nf = 0; nf < 2; ++nf) acc[mf][nf] = (f32x4)(0.f);

  for (int k0 = 0; k0 < K; k0 += 32) {
#pragma unroll
    for (int it = 0; it < 2; ++it) {
      int q = tid + it * 256;
      int r = q >> 3, kq = (q & 7) * 4;
      int grow = row0 + r;
      float4 v = make_float4(0.f, 0.f, 0.f, 0.f);
      if (grow < M) v = *reinterpret_cast<const float4*>(&X[(size_t)grow * K + k0 + kq]);
      u16x4 p = {f2bf(v.x), f2bf(v.y), f2bf(v.z), f2bf(v.w)};
      *reinterpret_cast<u16x4*>(&Xs[r][kq]) = p;
    }
#pragma unroll
    for (int it = 0; it < 2; ++it) {
      int q = tid + it * 256;
      int n = q >> 2, kq = (q & 3) * 8;
      bf16x8 wrow = *reinterpret_cast<const bf16x8*>(&Wbf[(size_t)n * K + k0 + kq]);
      *reinterpret_cast<bf16x8*>(&Bs[n][kq]) = wrow;
    }
    __syncthreads();
    bf16x8 a[4], b[2];
#pragma unroll
    for (int mf = 0; mf < 4; ++mf)
      a[mf] = *reinterpret_cast<const bf16x8*>(&Xs[mf * 16 + lr][lg * 8]);
#pragma unroll
    for (int nf = 0; nf < 2; ++nf)
      b[nf] = *reinterpret_cast<const bf16x8*>(&Bs[wv * 32 + nf * 16 + lr][lg * 8]);
#pragma unroll
    for (int mf = 0; mf < 4; ++mf)
#pragma unroll
      for (int nf = 0; nf < 2; ++nf)
        acc[mf][nf] = __builtin_amdgcn_mfma_f32_16x16x32_bf16(a[mf], b[nf], acc[mf][nf], 0, 0, 0);
    __syncthreads();
  }

  int col[2];
  float bv[2];
#pragma unroll
  for (int nf = 0; nf < 2; ++nf) {
    col[nf] = wv * 32 + nf * 16 + lr;
    bv[nf] = bias[col[nf]];
  }
#pragma unroll
  for (int mf = 0; mf < 4; ++mf)
#pragma unroll
    for (int reg = 0; reg < 4; ++reg) {
      int grow = row0 + mf * 16 + lg * 4 + reg;
      if (grow < M) {
#pragma unroll
        for (int nf = 0; nf < 2; ++nf)
          out[(size_t)grow * 128 + col[nf]] = f2bf(acc[mf][nf][reg] + bv[nf]);
      }
    }
}

// ------- MFMA update GEMM: X = concat(agg bf16, base f32) (M x 256); LN; ReLU -------
__global__ __launch_bounds__(256) void gemm_upd_mfma(const unsigned short* __restrict__ agg,
                                                     const float* __restrict__ base,
                                                     const unsigned short* __restrict__ Wbf,
                                                     const float* __restrict__ bias,
                                                     const float* __restrict__ lng,
                                                     const float* __restrict__ lnb,
                                                     float* __restrict__ out, int M) {
  constexpr int K = 256;
  __shared__ unsigned short Xs[64][40];
  __shared__ unsigned short Bs[128][40];
  __shared__ float sredS[64][4];
  __shared__ float sredQ[64][4];
  const int tid = threadIdx.x;
  const int lane = tid & 63, wv = tid >> 6;
  const int lr = lane & 15, lg = lane >> 4;
  const int row0 = blockIdx.x * 64;

  f32x4 acc[4][2];
#pragma unroll
  for (int mf = 0; mf < 4; ++mf)
#pragma unroll
    for (int nf = 0; nf < 2; ++nf) acc[mf][nf] = (f32x4)(0.f);

  for (int k0 = 0; k0 < K; k0 += 32) {
#pragma unroll
    for (int it = 0; it < 2; ++it) {
      int q = tid + it * 256;
      int r = q >> 3, kq = (q & 7) * 4;
      int grow = row0 + r, gk = k0 + kq;
      u16x4 p = {0, 0, 0, 0};
      if (grow < M) {
        if (gk < 128) {
          p = *reinterpret_cast<const u16x4*>(&agg[(size_t)grow * 128 + gk]);
        } else {
          float4 v = *reinterpret_cast<const float4*>(&base[(size_t)grow * 128 + (gk - 128)]);
          p = {f2bf(v.x), f2bf(v.y), f2bf(v.z), f2bf(v.w)};
        }
      }
      *reinterpret_cast<u16x4*>(&Xs[r][kq]) = p;
    }
#pragma unroll
    for (int it = 0; it < 2; ++it) {
      int q = tid + it * 256;
      int n = q >> 2, kq = (q & 3) * 8;
      bf16x8 wrow = *reinterpret_cast<const bf16x8*>(&Wbf[(size_t)n * K + k0 + kq]);
      *reinterpret_cast<bf16x8*>(&Bs[n][kq]) = wrow;
    }
    __syncthreads();
    bf16x8 a[4], b[2];
#pragma unroll
    for (int mf = 0; mf < 4; ++mf)
      a[mf] = *reinterpret_cast<const bf16x8*>(&Xs[mf * 16 + lr][lg * 8]);
#pragma unroll
    for (int nf = 0; nf < 2; ++nf)
      b[nf] = *reinterpret_cast<const bf16x8*>(&Bs[wv * 32 + nf * 16 + lr][lg * 8]);
#pragma unroll
    for (int mf = 0; mf < 4; ++mf)
#pragma unroll
      for (int nf = 0; nf < 2; ++nf)
        acc[mf][nf] = __builtin_amdgcn_mfma_f32_16x16x32_bf16(a[mf], b[nf], acc[mf][nf], 0, 0, 0);
    __syncthreads();
  }

  int col[2];
  float bv[2], gv[2], lv[2];
#pragma unroll
  for (int nf = 0; nf < 2; ++nf) {
    col[nf] = wv * 32 + nf * 16 + lr;
    bv[nf] = bias[col[nf]];
    gv[nf] = lng[col[nf]];
    lv[nf] = lnb[col[nf]];
  }

  float z[4][4][2];
#pragma unroll
  for (int mf = 0; mf < 4; ++mf)
#pragma unroll
    for (int reg = 0; reg < 4; ++reg) {
      float z0 = acc[mf][0][reg] + bv[0];
      float z1 = acc[mf][1][reg] + bv[1];
      z[mf][reg][0] = z0;
      z[mf][reg][1] = z1;
      float s = z0 + z1;
      float q = z0 * z0 + z1 * z1;
#pragma unroll
      for (int m = 1; m < 16; m <<= 1) {
        s += __shfl_xor(s, m);
        q += __shfl_xor(q, m);
      }
      if (lr == 0) {
        sredS[mf * 16 + lg * 4 + reg][wv] = s;
        sredQ[mf * 16 + lg * 4 + reg][wv] = q;
      }
    }
  __syncthreads();
#pragma unroll
  for (int mf = 0; mf < 4; ++mf)
#pragma unroll
    for (int reg = 0; reg < 4; ++reg) {
      int tr = mf * 16 + lg * 4 + reg;
      f32x4 S4 = *reinterpret_cast<const f32x4*>(&sredS[tr][0]);
      f32x4 Q4 = *reinterpret_cast<const f32x4*>(&sredQ[tr][0]);
      float S = S4[0] + S4[1] + S4[2] + S4[3];
      float Q = Q4[0] + Q4[1] + Q4[2] + Q4[3];
      float mean = S * (1.f / 128.f);
      float var = Q * (1.f / 128.f) - mean * mean;
      float rstd = rsqrtf(var + LN_EPS);
      int grow = row0 + tr;
      if (grow < M) {
#pragma unroll
        for (int nf = 0; nf < 2; ++nf) {
          float y = (z[mf][reg][nf] - mean) * rstd * gv[nf] + lv[nf];
          out[(size_t)grow * 128 + col[nf]] = fmaxf(y, 0.f);
        }
      }
    }
}

extern "C" void kernel_launch(void* const* d_in, const int* in_sizes, int n_in,
                              void* d_out, int out_size, void* d_ws, size_t ws_size,
                              hipStream_t stream) {
  const float* vh = (const float*)d_in[0];
  const float* ch = (const float*)d_in[1];
  const int* ei = (const int*)d_in[2];   // [ci(E), vi(E)]
  const float* ew = (const float*)d_in[3];
  const float* v2c_lin_w = (const float*)d_in[4];
  const float* v2c_lin_b = (const float*)d_in[5];
  const float* v2c_gate_w = (const float*)d_in[6];
  const float* v2c_gate_b = (const float*)d_in[7];
  const float* v2c_upd_w = (const float*)d_in[8];
  const float* v2c_upd_b = (const float*)d_in[9];
  const float* v2c_ln_g = (const float*)d_in[10];
  const float* v2c_ln_b = (const float*)d_in[11];
  const float* c2v_lin_w = (const float*)d_in[12];
  const float* c2v_lin_b = (const float*)d_in[13];
  const float* c2v_gate_w = (const float*)d_in[14];
  const float* c2v_gate_b = (const float*)d_in[15];
  const float* c2v_upd_w = (const float*)d_in[16];
  const float* c2v_upd_b = (const float*)d_in[17];
  const float* c2v_ln_g = (const float*)d_in[18];
  const float* c2v_ln_b = (const float*)d_in[19];

  const int N = in_sizes[0] / 128;
  const int C = in_sizes[1] / 128;
  const int E = in_sizes[3];
  const int* ci = ei;
  const int* vi = ei + E;

  unsigned short* tmpNV = (unsigned short*)d_ws;        // N*128 bf16: tmp_v, later agg_v
  unsigned short* aggC = tmpNV + (size_t)N * 128;       // C*128 bf16: agg_c, later tmp_c
  unsigned short* wbfLinV = aggC + (size_t)C * 128;     // 128*128
  unsigned short* wbfUpdV = wbfLinV + 128 * 128;        // 128*256
  unsigned short* wbfLinC = wbfUpdV + 128 * 256;        // 128*128
  unsigned short* wbfUpdC = wbfLinC + 128 * 128;        // 128*256
  int* offC = (int*)(wbfUpdC + 128 * 256);              // C+1
  int* offV = offC + (C + 1);                           // N+1
  // 8-byte align for int2
  size_t ofs = (size_t)(offV + (N + 1) - (int*)d_ws);
  ofs = (ofs + 1) & ~(size_t)1;
  int2* edataC = (int2*)((int*)d_ws + ofs);             // E
  int2* edataV = edataC + E;                            // E
  // sort scratch aliased into aggC region (dead until seg_reduce writes it)
  int* cntS = (int*)aggC;                               // max(C,N)
  int* curS = cntS + N;                                 // max(C,N)
  int* bsumS = curS + N;                                // ~256

  float* vhNew = (float*)d_out;
  float* chNew = (float*)d_out + (size_t)N * 128;

  // weight f32->bf16
  cvt_bf16<<<(128 * 128 + 255) / 256, 256, 0, stream>>>(v2c_lin_w, wbfLinV, 128 * 128);
  cvt_bf16<<<(128 * 256 + 255) / 256, 256, 0, stream>>>(v2c_upd_w, wbfUpdV, 128 * 256);
  cvt_bf16<<<(128 * 128 + 255) / 256, 256, 0, stream>>>(c2v_lin_w, wbfLinC, 128 * 128);
  cvt_bf16<<<(128 * 256 + 255) / 256, 256, 0, stream>>>(c2v_upd_w, wbfUpdC, 128 * 256);

  const int egrid = (E + 255) / 256;

  // ---- counting sort by ci (for v2c): edata = {vi, ew} ----
  hipMemsetAsync(cntS, 0, (size_t)C * sizeof(int), stream);
  hist_kernel<<<egrid, 256, 0, stream>>>(ci, cntS, E);
  {
    int nb = (C + 1023) / 1024;
    scan1<<<nb, 256, 0, stream>>>(cntS, offC, bsumS, C);
    scan2<<<1, 256, 0, stream>>>(bsumS, nb);
    scan3<<<(C + 1 + 255) / 256, 256, 0, stream>>>(offC, bsumS, C, E);
  }
  hipMemcpyAsync(curS, offC, (size_t)C * sizeof(int), hipMemcpyDeviceToDevice, stream);
  reorder_kernel<<<egrid, 256, 0, stream>>>(ci, vi, ew, curS, edataC, E);

  // ---- counting sort by vi (for c2v): edata = {ci, ew} ----
  hipMemsetAsync(cntS, 0, (size_t)N * sizeof(int), stream);
  hist_kernel<<<egrid, 256, 0, stream>>>(vi, cntS, E);
  {
    int nb = (N + 1023) / 1024;
    scan1<<<nb, 256, 0, stream>>>(cntS, offV, bsumS, N);
    scan2<<<1, 256, 0, stream>>>(bsumS, nb);
    scan3<<<(N + 1 + 255) / 256, 256, 0, stream>>>(offV, bsumS, N, E);
  }
  hipMemcpyAsync(curS, offV, (size_t)N * sizeof(int), hipMemcpyDeviceToDevice, stream);
  reorder_kernel<<<egrid, 256, 0, stream>>>(vi, ci, ew, curS, edataV, E);

  // ---- v2c ----
  gemm_lin_mfma<128><<<(N + 63) / 64, 256, 0, stream>>>(vh, wbfLinV, v2c_lin_b, tmpNV, N);
  seg_reduce<<<(C + 3) / 4, 256, 0, stream>>>(offC, edataC, v2c_gate_w, v2c_gate_b,
                                              tmpNV, aggC, C);
  gemm_upd_mfma<<<(C + 63) / 64, 256, 0, stream>>>(aggC, ch, wbfUpdV, v2c_upd_b,
                                                   v2c_ln_g, v2c_ln_b, chNew, C);

  // ---- c2v ----
  unsigned short* tmpC = aggC;   // reuse (agg_c dead after gemm_upd)
  gemm_lin_mfma<128><<<(C + 63) / 64, 256, 0, stream>>>(chNew, wbfLinC, c2v_lin_b, tmpC, C);
  unsigned short* aggV = tmpNV;  // reuse (tmp_v dead after v2c seg_reduce)
  seg_reduce<<<(N + 3) / 4, 256, 0, stream>>>(offV, edataV, c2v_gate_w, c2v_gate_b,
                                              tmpC, aggV, N);
  gemm_upd_mfma<<<(N + 63) / 64, 256, 0, stream>>>(aggV, vh, wbfUpdC, c2v_upd_b,
                                                   c2v_ln_g, c2v_ln_b, vhNew, N);
}